// Round 15
// baseline (204.090 us; speedup 1.0000x reference)
//
#include <hip/hip_runtime.h>

#define NN 50000
#define NE 800000
#define NBUCK ((NN + 255) / 256) // 196 dst-buckets of 256 nodes
#define EPB 4096                 // edges per k_bin block (16 per thread)
#define BINB ((NE + EPB - 1) / EPB)     // 196 bin blocks
#define PACKB 208                // packall blocks (53248 items / 256)
#define BCAP 8192                // padded per-bucket capacity (mean 4082, max~4.4k)
#define QCAP 512                 // per-block LDS q capacity (mean 256, ~16 sigma)
#define LIN12_BLOCKS ((NN + 63) / 64)   // 782

typedef unsigned int uint32;
typedef unsigned short ushort16;
typedef __attribute__((ext_vector_type(8))) short bf16x8;
typedef __attribute__((ext_vector_type(4))) float f32x4;
typedef __attribute__((ext_vector_type(2))) float f32x2;

__device__ __forceinline__ ushort16 f2bf(float f) {
    uint32 u = __float_as_uint(f);
    u += 0x7fff + ((u >> 16) & 1);      // round-to-nearest-even
    return (ushort16)(u >> 16);
}
__device__ __forceinline__ float bf_lo(uint32 u) {
    return __uint_as_float(u << 16);
}
__device__ __forceinline__ float bf_hi(uint32 u) {
    return __uint_as_float(u & 0xffff0000u);
}
__device__ __forceinline__ f32x2 splat2(float s) {
    f32x2 r; r[0] = s; r[1] = s; return r;
}
__device__ __forceinline__ bf16x8 pack8(const float4 a, const float4 b) {
    union { bf16x8 v; ushort16 u[8]; } r;
    r.u[0] = f2bf(a.x); r.u[1] = f2bf(a.y); r.u[2] = f2bf(a.z); r.u[3] = f2bf(a.w);
    r.u[4] = f2bf(b.x); r.u[5] = f2bf(b.y); r.u[6] = f2bf(b.z); r.u[7] = f2bf(b.w);
    return r.v;
}
__device__ __forceinline__ float4 softq(const float4 ts, const float4 td,
                                        const float4 tc, const float invdeg) {
    const float l0 = ts.x - td.x + tc.x;
    const float l1 = ts.y - td.y + tc.y;
    const float l2 = ts.z - td.z + tc.z;
    const float l3 = ts.w - td.w + tc.w;
    const float mx = fmaxf(fmaxf(l0, l1), fmaxf(l2, l3));
    const float e0 = __expf(l0 - mx);
    const float e1 = __expf(l1 - mx);
    const float e2 = __expf(l2 - mx);
    const float e3 = __expf(l3 - mx);
    const float sden = invdeg / (e0 + e1 + e2 + e3);
    return make_float4(e0 * sden, e1 * sden, e2 * sden, e3 * sden);
}

// ---------------------------------------------------------------------------
// Butterfly multi-reduce: 16 values/lane over the 16 m-lanes of a quad.
// ---------------------------------------------------------------------------
__device__ __forceinline__ float multireduce16(const float* tl, int m) {
    float t8[8];
#pragma unroll
    for (int i = 0; i < 8; ++i) {
        const float a0 = tl[2 * i], b0 = tl[2 * i + 1];
        const float oa = __shfl_xor(a0, 1, 64), ob = __shfl_xor(b0, 1, 64);
        t8[i] = ((m & 1) == 0) ? (a0 + oa) : (b0 + ob);
    }
    float t4[4];
#pragma unroll
    for (int i = 0; i < 4; ++i) {
        const float a0 = t8[2 * i], b0 = t8[2 * i + 1];
        const float oa = __shfl_xor(a0, 2, 64), ob = __shfl_xor(b0, 2, 64);
        t4[i] = ((m & 2) == 0) ? (a0 + oa) : (b0 + ob);
    }
    float t2[2];
#pragma unroll
    for (int i = 0; i < 2; ++i) {
        const float a0 = t4[2 * i], b0 = t4[2 * i + 1];
        const float oa = __shfl_xor(a0, 4, 64), ob = __shfl_xor(b0, 4, 64);
        t2[i] = ((m & 4) == 0) ? (a0 + oa) : (b0 + ob);
    }
    const float a0 = t2[0], b0 = t2[1];
    const float oa = __shfl_xor(a0, 8, 64), ob = __shfl_xor(b0, 8, 64);
    return ((m & 8) == 0) ? (a0 + oa) : (b0 + ob);
}

// ---------------------------------------------------------------------------
// packall body: weight pre-packs (bcnt zero now done by hipMemsetAsync).
// ---------------------------------------------------------------------------
__device__ __forceinline__ ushort16 packp_val(const float* __restrict__ w, int i) {
    const int j  = i & 7;
    const int ln = (i >> 3) & 63;
    const int s  = (i >> 9) & 7;
    const int cc = i >> 12;
    const int k  = s * 32 + ((ln >> 4) * 8) + j;    // zcat idx (k-dim)
    const int n  = cc * 16 + (ln & 15);             // output col
    return f2bf(w[(k >> 2) * 256 + (k & 3) * 64 + n]);
}

__device__ void packall_body(const int bid,
    const float* __restrict__ w1, const float* __restrict__ w2,
    const float* __restrict__ wc1, const float* __restrict__ wc2,
    const float* __restrict__ wl3,
    ushort16* __restrict__ pw12, ushort16* __restrict__ pwc1,
    ushort16* __restrict__ pwc2, ushort16* __restrict__ pwl3)
{
    const int gid = bid * 256 + threadIdx.x;
    if (gid < 16384) {
        const int i = gid;
        const int j  = i & 7;
        const int ln = (i >> 3) & 63;
        const int s  = (i >> 9) & 3;
        const int cc = i >> 11;
        const int k  = s * 32 + ((ln >> 4) * 8) + j;    // 0..127
        const int n  = cc * 16 + (ln & 15);             // 0..127
        pw12[i] = f2bf((n < 64) ? w1[k * 64 + n] : w2[k * 64 + (n - 64)]);
    } else if (gid < 32768) {
        pwc1[gid - 16384] = packp_val(wc1, gid - 16384);
    } else if (gid < 49152) {
        pwc2[gid - 32768] = packp_val(wc2, gid - 32768);
    } else if (gid < 53248) {
        const int i = gid - 49152;                      // 0..4095
        const int j  = i & 7;
        const int ln = (i >> 3) & 63;
        const int s  = (i >> 9) & 1;
        const int cc = i >> 10;                         // 0..3
        const int k  = s * 32 + ((ln >> 4) * 8) + j;    // 0..63
        const int n  = cc * 16 + (ln & 15);             // 0..63
        pwl3[i] = f2bf(wl3[k * 64 + n]);
    }
}

// ---------------------------------------------------------------------------
// bin body: appends edges into bucket-PADDED `pairs` (bcnt pre-zeroed).
// ---------------------------------------------------------------------------
__device__ void bin_body(const int bid, const int* __restrict__ ei,
                         int* __restrict__ bcnt, uint32* __restrict__ pairs)
{
    __shared__ int hist[NBUCK];
    __shared__ int gbase[NBUCK];
    const int t = threadIdx.x;
    const int base = bid * EPB;

    for (int b = t; b < NBUCK; b += 256) hist[b] = 0;
    __syncthreads();

    uint32 pk[16];
    int bk[16], rk[16];
#pragma unroll
    for (int k = 0; k < 16; ++k) {
        const int e = base + k * 256 + t;
        if (e < NE) {
            const int s = ei[e];
            const int d = ei[NE + e];
            bk[k] = d >> 8;
            pk[k] = (uint32)s | ((uint32)(d & 255) << 16);
            rk[k] = atomicAdd(&hist[bk[k]], 1);
        }
    }
    __syncthreads();

    for (int b = t; b < NBUCK; b += 256)
        gbase[b] = hist[b] ? atomicAdd(&bcnt[b], hist[b]) : 0;
    __syncthreads();

#pragma unroll
    for (int k = 0; k < 16; ++k) {
        const int e = base + k * 256 + t;
        if (e < NE) pairs[(size_t)bk[k] * BCAP + gbase[bk[k]] + rk[k]] = pk[k];
    }
}

// ---------------------------------------------------------------------------
// k_binpack: MERGED bin + packall (independent work, block-partitioned).
// ---------------------------------------------------------------------------
__global__ __launch_bounds__(256) void k_binpack(
    const int* __restrict__ ei, int* __restrict__ bcnt,
    uint32* __restrict__ pairs,
    const float* __restrict__ w1, const float* __restrict__ w2,
    const float* __restrict__ wc1, const float* __restrict__ wc2,
    const float* __restrict__ wl3,
    ushort16* __restrict__ pw12, ushort16* __restrict__ pwc1,
    ushort16* __restrict__ pwc2, ushort16* __restrict__ pwl3)
{
    if (blockIdx.x < BINB) {
        bin_body(blockIdx.x, ei, bcnt, pairs);
    } else {
        packall_body(blockIdx.x - BINB, w1, w2, wc1, wc2, wl3,
                     pw12, pwc1, pwc2, pwl3);
    }
}

// ---------------------------------------------------------------------------
// binscat body (one block per bucket): derives bucket bases + per-node
// row_ptr in-block and scatters ssrc within its ~16KB window.
// ---------------------------------------------------------------------------
__device__ void binscat_body(const int bid,
                             const uint32* __restrict__ pairs,
                             const int* __restrict__ bcnt,
                             int* __restrict__ row_ptr,
                             int* __restrict__ ssrc)
{
    __shared__ int sb[256];
    __shared__ int hist[256];
    __shared__ int s[256];
    __shared__ int lptr[256];
    __shared__ int lcur[256];
    const int b = bid;
    const int t = threadIdx.x;
    const int total = bcnt[b];
    const uint32* pb = pairs + (size_t)b * BCAP;

    // bucket-level exclusive base via block-local scan of all bucket counts
    sb[t] = (t < NBUCK) ? bcnt[t] : 0;
    __syncthreads();
    for (int off = 1; off < 256; off <<= 1) {
        const int v = (t >= off) ? sb[t - off] : 0;
        __syncthreads();
        sb[t] += v;
        __syncthreads();
    }
    const int base = sb[b] - total;
    if (b == 0 && t == 0) row_ptr[NN] = NE;

    hist[t] = 0;
    __syncthreads();
    for (int e = t; e < total; e += 256) atomicAdd(&hist[pb[e] >> 16], 1);
    __syncthreads();

    const int v = hist[t];
    s[t] = v;
    __syncthreads();
    for (int off = 1; off < 256; off <<= 1) {
        const int u = (t >= off) ? s[t - off] : 0;
        __syncthreads();
        s[t] += u;
        __syncthreads();
    }
    const int excl = base + s[t] - v;
    lptr[t] = excl;
    lcur[t] = 0;
    const int n = (b << 8) + t;
    if (n < NN) row_ptr[n] = excl;
    __syncthreads();

    for (int e = t; e < total; e += 256) {
        const uint32 p = pb[e];
        const int d = p >> 16;
        const int r = atomicAdd(&lcur[d], 1);
        ssrc[lptr[d] + r] = (int)(p & 0xffffu);
    }
}

// ---------------------------------------------------------------------------
// lin12 body (MFMA): [a_bf16 | skip] = x @ [W1 | W2] + [b1 | b2], with the
// attention projection t = a @ u fused into the epilogue.
// ---------------------------------------------------------------------------
__device__ void lin12_body(const int bid,
                           const float* __restrict__ x,
                           const ushort16* __restrict__ pw,
                           const float* __restrict__ b1,
                           const float* __restrict__ b2,
                           const float* __restrict__ u,
                           ushort16* __restrict__ ab,
                           float* __restrict__ skip,
                           float* __restrict__ tOut)
{
    const int tid = threadIdx.x;
    const int lane = tid & 63;
    const int g = tid >> 6;
    const int m = lane & 15;
    const int quad = lane >> 4;
    const int rowBase = bid * 64 + g * 16;

    const int arow = min(rowBase + m, NN - 1);
    const float* xr = x + (size_t)arow * 128 + quad * 8;

    f32x4 acc[8];
#pragma unroll
    for (int c = 0; c < 8; ++c)
#pragma unroll
        for (int r = 0; r < 4; ++r) acc[c][r] = 0.f;

#pragma unroll
    for (int s = 0; s < 4; ++s) {
        const float4 xa = *(const float4*)(xr + s * 32);
        const float4 xb = *(const float4*)(xr + s * 32 + 4);
        const bf16x8 af = pack8(xa, xb);
#pragma unroll
        for (int c = 0; c < 8; ++c) {
            const bf16x8 bf = *(const bf16x8*)&pw[((c * 4 + s) * 64 + lane) * 8];
            acc[c] = __builtin_amdgcn_mfma_f32_16x16x32_bf16(af, bf, acc[c], 0, 0, 0);
        }
    }

    float tl[16];
#pragma unroll
    for (int i = 0; i < 16; ++i) tl[i] = 0.f;

#pragma unroll
    for (int c = 0; c < 8; ++c) {
        const int colg = c * 16 + m;
        const float bv = (colg < 64) ? b1[colg] : b2[colg - 64];
#pragma unroll
        for (int reg = 0; reg < 4; ++reg) {
            const float v = acc[c][reg] + bv;
            const int gr = rowBase + quad * 4 + reg;
            if (gr < NN) {
                if (c < 4) ab[gr * 64 + colg] = f2bf(v);
                else       skip[gr * 64 + (colg - 64)] = v;
            }
            if (c < 4) {
                const float4 uv = ((const float4*)u)[colg];
                tl[reg * 4 + 0] += v * uv.x;
                tl[reg * 4 + 1] += v * uv.y;
                tl[reg * 4 + 2] += v * uv.z;
                tl[reg * 4 + 3] += v * uv.w;
            }
        }
    }

    const float tv = multireduce16(tl, m);
    const int gidx = rowBase * 4 + (quad << 4) + m;  // = row*4 + h, contiguous
    if (gidx < NN * 4) tOut[gidx] = tv;
}

// ---------------------------------------------------------------------------
// k_bslin: MERGED binscat + lin12 (independent work, block-partitioned).
// ---------------------------------------------------------------------------
__global__ __launch_bounds__(256) void k_bslin(
    const uint32* __restrict__ pairs, const int* __restrict__ bcnt,
    int* __restrict__ row_ptr, int* __restrict__ ssrc,
    const float* __restrict__ x, const ushort16* __restrict__ pw,
    const float* __restrict__ b1, const float* __restrict__ b2,
    const float* __restrict__ u,
    ushort16* __restrict__ ab, float* __restrict__ skip,
    float* __restrict__ tOut)
{
    if (blockIdx.x < NBUCK) {
        binscat_body(blockIdx.x, pairs, bcnt, row_ptr, ssrc);
    } else {
        lin12_body(blockIdx.x - NBUCK, x, pw, b1, b2, u, ab, skip, tOut);
    }
}

// ---------------------------------------------------------------------------
// k_aggpost: FUSED aggregation + post-GEMM (+ optional fused lin3).
// Block = 16 nodes, 4 waves x 4 nodes/wave. Per-wave phase 0: softmax q for
// own 4 nodes' edges -> {q1,q2,q3,src} in LDS (q0 = invdeg-q1-q2-q3).
// Phase 1: R7's half-split body, 8/2/1 ladder, PACKED f32x2 accumulation.
// Phase 2: 16x256 LDS tile -> MFMA post-GEMM + bias + skip + relu (+fused t).
//   Layer-1 mode additionally runs lin3 (h @ W3 + b3 -> skip) in-block.
// hl tile ALIASES ql (ql dead after phase-1 barrier; hl written after it).
// LDS ~17.4 KB.
// ---------------------------------------------------------------------------
__global__ __launch_bounds__(256) void k_aggpost(
    const int* __restrict__ row_ptr, const int* __restrict__ ssrc,
    const float* __restrict__ t, const uint32* __restrict__ abu,
    const float* __restrict__ c,
    const ushort16* __restrict__ pw, const float* __restrict__ bias,
    float* skip,
    float* __restrict__ out, ushort16* __restrict__ outb,
    const float* __restrict__ uproj, float* __restrict__ tOut,
    const ushort16* __restrict__ pwl3, const float* __restrict__ b3)
{
    __shared__ float4 ql[QCAP];         // 8 KB: {q1,q2,q3, src_bits}; phase 2
                                        // reuses first 2 KB as the hl tile
    __shared__ char zl[16 * 512];       // 8 KB: 16 nodes x 256 bf16, swizzled
    __shared__ float t_lds[4][64];
    __shared__ float4 tnode[16];
    __shared__ float invdegs[16];
    char* hl = (char*)ql;               // 2 KB h bf16 tile for fused lin3

    const int tid = threadIdx.x;
    const int lane = tid & 63;
    const int w = tid >> 6;
    const int half = lane >> 5;
    const int u = lane & 31;
    const int nodeBase = blockIdx.x * 16;

    const float4 tc = *(const float4*)c;

    // per-wave row_ptr boundaries: lanes 0..4 -> own nodes, 5 -> block start,
    // 6 -> block end (nodeBase+16).
    int rr = 0;
    if (lane < 7) {
        const int off = (lane < 5) ? (w * 4 + lane) : ((lane == 5) ? 0 : 16);
        rr = row_ptr[nodeBase + off];
    }
    const int rp0 = __shfl(rr, 0, 64);
    const int rp1 = __shfl(rr, 1, 64);
    const int rp2 = __shfl(rr, 2, 64);
    const int rp3 = __shfl(rr, 3, 64);
    const int rp4 = __shfl(rr, 4, 64);
    const int r0b = __shfl(rr, 5, 64);
    const int r1b = __shfl(rr, 6, 64);

    if (lane < 4) {
        tnode[w * 4 + lane] = ((const float4*)t)[nodeBase + w * 4 + lane];
        const int a = (lane == 0) ? rp0 : (lane == 1) ? rp1 : (lane == 2) ? rp2 : rp3;
        const int b = (lane == 0) ? rp1 : (lane == 1) ? rp2 : (lane == 2) ? rp3 : rp4;
        invdegs[w * 4 + lane] = (b > a) ? 1.f / (float)(b - a) : 0.f;
    }

    const bool fit = (r1b - r0b) <= QCAP;

    // ---- phase 0 (per-wave): q for own segment [rp0, rp4) -> LDS slice ----
    if (fit) {
        for (int i = rp0 + lane; i < rp4; i += 64) {
            const int se = ssrc[i];
            const int dl = (i >= rp1) + (i >= rp2) + (i >= rp3);
            const float4 ts = ((const float4*)t)[se];
            const float4 q = softq(ts, tnode[w * 4 + dl], tc, invdegs[w * 4 + dl]);
            ql[i - r0b] = make_float4(q.y, q.z, q.w, __int_as_float(se));
        }
    }

    // ---- phase 1: half-split 8/2/1 ladder, packed f32x2 accumulation ----
#define ACCUM3(QA, AV)                                                 \
    {                                                                  \
        const float q0 = invdeg - (QA).x - (QA).y - (QA).z;            \
        f32x2 vv; vv[0] = bf_lo(AV); vv[1] = bf_hi(AV);                \
        zz0 = __builtin_elementwise_fma(vv, splat2(q0), zz0);          \
        zz1 = __builtin_elementwise_fma(vv, splat2((QA).x), zz1);      \
        zz2 = __builtin_elementwise_fma(vv, splat2((QA).y), zz2);      \
        zz3 = __builtin_elementwise_fma(vv, splat2((QA).z), zz3);      \
    }
#define ACCUM4(Q4, AV)                                                 \
    {                                                                  \
        f32x2 vv; vv[0] = bf_lo(AV); vv[1] = bf_hi(AV);                \
        zz0 = __builtin_elementwise_fma(vv, splat2((Q4).x), zz0);      \
        zz1 = __builtin_elementwise_fma(vv, splat2((Q4).y), zz1);      \
        zz2 = __builtin_elementwise_fma(vv, splat2((Q4).z), zz2);      \
        zz3 = __builtin_elementwise_fma(vv, splat2((Q4).w), zz3);      \
    }

#pragma unroll
    for (int nn = 0; nn < 4; ++nn) {
        const int nloc = w * 4 + nn;
        const int r0 = (nn == 0) ? rp0 : (nn == 1) ? rp1 : (nn == 2) ? rp2 : rp3;
        const int r1 = (nn == 0) ? rp1 : (nn == 1) ? rp2 : (nn == 2) ? rp3 : rp4;
        const float invdeg = (r1 > r0) ? 1.f / (float)(r1 - r0) : 0.f;

        f32x2 zz0 = {0.f, 0.f}, zz1 = {0.f, 0.f};
        f32x2 zz2 = {0.f, 0.f}, zz3 = {0.f, 0.f};

        if (fit) {
            const float4* qb = ql - r0b;
            int idx = r0;
            for (; idx + 7 < r1; idx += 8) {
                const float4 qa0 = qb[idx + half];
                const float4 qa1 = qb[idx + 2 + half];
                const float4 qa2 = qb[idx + 4 + half];
                const float4 qa3 = qb[idx + 6 + half];
                const uint32 av0 = abu[__float_as_int(qa0.w) * 32 + u];
                const uint32 av1 = abu[__float_as_int(qa1.w) * 32 + u];
                const uint32 av2 = abu[__float_as_int(qa2.w) * 32 + u];
                const uint32 av3 = abu[__float_as_int(qa3.w) * 32 + u];
                ACCUM3(qa0, av0) ACCUM3(qa1, av1)
                ACCUM3(qa2, av2) ACCUM3(qa3, av3)
            }
            for (; idx + 1 < r1; idx += 2) {
                const float4 qa = qb[idx + half];
                const uint32 av = abu[__float_as_int(qa.w) * 32 + u];
                ACCUM3(qa, av)
            }
            if (idx < r1 && half == 0) {
                const float4 qa = qb[idx];
                const uint32 av = abu[__float_as_int(qa.w) * 32 + u];
                ACCUM3(qa, av)
            }
        } else {
            // never-taken in practice: recompute q inline (no LDS capacity)
            const float4 td = tnode[nloc];
            int idx = r0;
            for (; idx + 1 < r1; idx += 2) {
                const int se = ssrc[idx + half];
                const uint32 av = abu[se * 32 + u];
                const float4 q4 = softq(((const float4*)t)[se], td, tc, invdeg);
                ACCUM4(q4, av)
            }
            if (idx < r1 && half == 0) {
                const int se = ssrc[idx];
                const uint32 av = abu[se * 32 + u];
                const float4 q4 = softq(((const float4*)t)[se], td, tc, invdeg);
                ACCUM4(q4, av)
            }
        }
#undef ACCUM3
#undef ACCUM4

        float z00 = zz0[0], z01 = zz0[1];
        float z10 = zz1[0], z11 = zz1[1];
        float z20 = zz2[0], z21 = zz2[1];
        float z30 = zz3[0], z31 = zz3[1];

        z00 += __shfl_xor(z00, 32, 64); z01 += __shfl_xor(z01, 32, 64);
        z10 += __shfl_xor(z10, 32, 64); z11 += __shfl_xor(z11, 32, 64);
        z20 += __shfl_xor(z20, 32, 64); z21 += __shfl_xor(z21, 32, 64);
        z30 += __shfl_xor(z30, 32, 64); z31 += __shfl_xor(z31, 32, 64);

        if (half == 0) {
            uint4 pk;
            pk.x = (uint32)f2bf(z00) | ((uint32)f2bf(z10) << 16);
            pk.y = (uint32)f2bf(z20) | ((uint32)f2bf(z30) << 16);
            pk.z = (uint32)f2bf(z01) | ((uint32)f2bf(z11) << 16);
            pk.w = (uint32)f2bf(z21) | ((uint32)f2bf(z31) << 16);
            *(uint4*)(zl + nloc * 512 + ((u * 16) ^ ((nloc & 7) << 4))) = pk;
        }
    }
    __syncthreads();     // ql dead from here; hl (aliased) becomes live

    // ---- phase 2: post-GEMM from LDS (wave w -> cols w*16..+15) ----
    const int m = lane & 15;
    const int quad = lane >> 4;

    f32x4 acc;
#pragma unroll
    for (int r = 0; r < 4; ++r) acc[r] = 0.f;

#pragma unroll
    for (int s = 0; s < 8; ++s) {
        const bf16x8 af = *(const bf16x8*)(zl + m * 512 +
                            ((s * 64 + quad * 16) ^ ((m & 7) << 4)));
        const bf16x8 bf = *(const bf16x8*)&pw[((w * 8 + s) * 64 + lane) * 8];
        acc = __builtin_amdgcn_mfma_f32_16x16x32_bf16(af, bf, acc, 0, 0, 0);
    }

    const int colg = w * 16 + m;
    const float bv = bias[colg];

    float tl[16];
#pragma unroll
    for (int i = 0; i < 16; ++i) tl[i] = 0.f;

#pragma unroll
    for (int reg = 0; reg < 4; ++reg) {
        const int gr = nodeBase + quad * 4 + reg;          // always < NN (16|NN)
        const float v = fmaxf(acc[reg] + bv + skip[gr * 64 + colg], 0.f);
        if (out)  out[gr * 64 + colg]  = v;
        if (outb) outb[gr * 64 + colg] = f2bf(v);
        if (pwl3) {
            const int row = quad * 4 + reg;
            *(ushort16*)(hl + ((row * 128 + colg * 2) ^ ((row & 7) << 4))) = f2bf(v);
        }
        if (tOut) {
            const float4 uv = ((const float4*)uproj)[colg];
            tl[reg * 4 + 0] += v * uv.x;
            tl[reg * 4 + 1] += v * uv.y;
            tl[reg * 4 + 2] += v * uv.z;
            tl[reg * 4 + 3] += v * uv.w;
        }
    }

    if (tOut) {
        const float tv = multireduce16(tl, m);   // wave-partial over its 16 cols
        t_lds[w][lane] = tv;
    }
    __syncthreads();

    if (tOut && w == 0) {
        const float tvf = t_lds[0][lane] + t_lds[1][lane] +
                          t_lds[2][lane] + t_lds[3][lane];
        tOut[nodeBase * 4 + lane] = tvf;         // row*4+h, contiguous 64 floats
    }

    // ---- fused lin3 (layer-1 only): skip = h @ W3 + b3 for this block ----
    if (pwl3) {
        f32x4 acc3;
#pragma unroll
        for (int r = 0; r < 4; ++r) acc3[r] = 0.f;
#pragma unroll
        for (int s = 0; s < 2; ++s) {
            const bf16x8 af = *(const bf16x8*)(hl +
                                ((m * 128 + quad * 16 + s * 64) ^ ((m & 7) << 4)));
            const bf16x8 bf = *(const bf16x8*)&pwl3[((w * 2 + s) * 64 + lane) * 8];
            acc3 = __builtin_amdgcn_mfma_f32_16x16x32_bf16(af, bf, acc3, 0, 0, 0);
        }
        const float b3v = b3[colg];
#pragma unroll
        for (int reg = 0; reg < 4; ++reg) {
            const int gr = nodeBase + quad * 4 + reg;
            skip[gr * 64 + colg] = acc3[reg] + b3v;
        }
    }
}

extern "C" void kernel_launch(void* const* d_in, const int* in_sizes, int n_in,
                              void* d_out, int out_size, void* d_ws, size_t ws_size,
                              hipStream_t stream) {
    const float* x       = (const float*)d_in[0];
    const int*   ei      = (const int*)d_in[1];   // [2, NE] int32
    const float* lin1_w  = (const float*)d_in[2];
    const float* lin1_b  = (const float*)d_in[3];
    const float* lin2_w  = (const float*)d_in[4];
    const float* lin2_b  = (const float*)d_in[5];
    const float* lin3_w  = (const float*)d_in[6];
    const float* lin3_b  = (const float*)d_in[7];
    const float* conv1_w = (const float*)d_in[8];
    const float* conv1_u = (const float*)d_in[9];
    const float* conv1_c = (const float*)d_in[10];
    const float* conv1_bias = (const float*)d_in[11];
    const float* conv2_w = (const float*)d_in[12];
    const float* conv2_u = (const float*)d_in[13];
    const float* conv2_c = (const float*)d_in[14];
    const float* conv2_bias = (const float*)d_in[15];
    float* out = (float*)d_out;

    // workspace layout (16B-aligned sections)
    char* p = (char*)d_ws;
    float* skip   = (float*)p;           p += (size_t)NN * 64 * 4;
    float* tt     = (float*)p;           p += (size_t)NN * 4 * 4;   // t (layer 1)
    float* tt2    = (float*)p;           p += (size_t)NN * 4 * 4;   // t (layer 2)
    ushort16* ab  = (ushort16*)p;        p += (size_t)NN * 64 * 2;  // bf16 a
    ushort16* hb  = (ushort16*)p;        p += (size_t)NN * 64 * 2;  // bf16 h
    ushort16* pw12 = (ushort16*)p;       p += 16384 * 2;            // packed [W1|W2]
    ushort16* pwc1 = (ushort16*)p;       p += 16384 * 2;            // packed conv1_w
    ushort16* pwc2 = (ushort16*)p;       p += 16384 * 2;            // packed conv2_w
    ushort16* pwl3 = (ushort16*)p;       p += 4096 * 2;             // packed lin3_w
    int* ssrc     = (int*)p;             p += (size_t)NE * 4;
    int* row_ptr  = (int*)p;             p += (size_t)(NN + 1) * 4;
    int* bcnt     = (int*)p;             p += 256 * 4;              // bucket cursors
    uint32* pairs = (uint32*)p;          p += (size_t)NBUCK * BCAP * 4; // padded bins

    // ---- bcnt zero + merged {CSR pass A | weight pre-pack} ----
    hipMemsetAsync(bcnt, 0, 256 * sizeof(int), stream);
    k_binpack<<<BINB + PACKB, 256, 0, stream>>>(ei, bcnt, pairs,
                                                lin1_w, lin2_w, conv1_w, conv2_w,
                                                lin3_w, pw12, pwc1, pwc2, pwl3);

    // ---- merged CSR scatter + lin12 (independent, one dispatch) ----
    k_bslin<<<NBUCK + LIN12_BLOCKS, 256, 0, stream>>>(pairs, bcnt, row_ptr, ssrc,
                                                      x, pw12, lin1_b, lin2_b,
                                                      conv1_u, ab, skip, tt);

    // ---- layer 1: fused agg + post + t2-projection + lin3 ----
    k_aggpost<<<NN / 16, 256, 0, stream>>>(row_ptr, ssrc, tt,
                                           (const uint32*)ab, conv1_c,
                                           pwc1, conv1_bias, skip,
                                           nullptr, hb, conv2_u, tt2,
                                           pwl3, lin3_b);

    // ---- layer 2 ----
    k_aggpost<<<NN / 16, 256, 0, stream>>>(row_ptr, ssrc, tt2,
                                           (const uint32*)hb, conv2_c,
                                           pwc2, conv2_bias, skip,
                                           out, nullptr, nullptr, nullptr,
                                           nullptr, nullptr);
}

// Round 16
// 199.528 us; speedup vs baseline: 1.0229x; 1.0229x over previous
//
#include <hip/hip_runtime.h>

#define NN 50000
#define NE 800000
#define NBUCK ((NN + 255) / 256) // 196 dst-buckets of 256 nodes
#define EPB 4096                 // edges per k_bin block (16 per thread)
#define BCAP 8192                // padded per-bucket capacity (mean 4082, max~4.4k)
#define QCAP 512                 // per-block LDS q capacity (mean 256, ~16 sigma)
#define LIN12_BLOCKS ((NN + 63) / 64)   // 782

typedef unsigned int uint32;
typedef unsigned short ushort16;
typedef __attribute__((ext_vector_type(8))) short bf16x8;
typedef __attribute__((ext_vector_type(4))) float f32x4;
typedef __attribute__((ext_vector_type(2))) float f32x2;

__device__ __forceinline__ ushort16 f2bf(float f) {
    uint32 u = __float_as_uint(f);
    u += 0x7fff + ((u >> 16) & 1);      // round-to-nearest-even
    return (ushort16)(u >> 16);
}
__device__ __forceinline__ float bf_lo(uint32 u) {
    return __uint_as_float(u << 16);
}
__device__ __forceinline__ float bf_hi(uint32 u) {
    return __uint_as_float(u & 0xffff0000u);
}
__device__ __forceinline__ f32x2 splat2(float s) {
    f32x2 r; r[0] = s; r[1] = s; return r;
}
__device__ __forceinline__ bf16x8 pack8(const float4 a, const float4 b) {
    union { bf16x8 v; ushort16 u[8]; } r;
    r.u[0] = f2bf(a.x); r.u[1] = f2bf(a.y); r.u[2] = f2bf(a.z); r.u[3] = f2bf(a.w);
    r.u[4] = f2bf(b.x); r.u[5] = f2bf(b.y); r.u[6] = f2bf(b.z); r.u[7] = f2bf(b.w);
    return r.v;
}
__device__ __forceinline__ float4 softq(const float4 ts, const float4 td,
                                        const float4 tc, const float invdeg) {
    const float l0 = ts.x - td.x + tc.x;
    const float l1 = ts.y - td.y + tc.y;
    const float l2 = ts.z - td.z + tc.z;
    const float l3 = ts.w - td.w + tc.w;
    const float mx = fmaxf(fmaxf(l0, l1), fmaxf(l2, l3));
    const float e0 = __expf(l0 - mx);
    const float e1 = __expf(l1 - mx);
    const float e2 = __expf(l2 - mx);
    const float e3 = __expf(l3 - mx);
    const float sden = invdeg / (e0 + e1 + e2 + e3);
    return make_float4(e0 * sden, e1 * sden, e2 * sden, e3 * sden);
}

// ---------------------------------------------------------------------------
// Butterfly multi-reduce: 16 values/lane over the 16 m-lanes of a quad.
// ---------------------------------------------------------------------------
__device__ __forceinline__ float multireduce16(const float* tl, int m) {
    float t8[8];
#pragma unroll
    for (int i = 0; i < 8; ++i) {
        const float a0 = tl[2 * i], b0 = tl[2 * i + 1];
        const float oa = __shfl_xor(a0, 1, 64), ob = __shfl_xor(b0, 1, 64);
        t8[i] = ((m & 1) == 0) ? (a0 + oa) : (b0 + ob);
    }
    float t4[4];
#pragma unroll
    for (int i = 0; i < 4; ++i) {
        const float a0 = t8[2 * i], b0 = t8[2 * i + 1];
        const float oa = __shfl_xor(a0, 2, 64), ob = __shfl_xor(b0, 2, 64);
        t4[i] = ((m & 2) == 0) ? (a0 + oa) : (b0 + ob);
    }
    float t2[2];
#pragma unroll
    for (int i = 0; i < 2; ++i) {
        const float a0 = t4[2 * i], b0 = t4[2 * i + 1];
        const float oa = __shfl_xor(a0, 4, 64), ob = __shfl_xor(b0, 4, 64);
        t2[i] = ((m & 4) == 0) ? (a0 + oa) : (b0 + ob);
    }
    const float a0 = t2[0], b0 = t2[1];
    const float oa = __shfl_xor(a0, 8, 64), ob = __shfl_xor(b0, 8, 64);
    return ((m & 8) == 0) ? (a0 + oa) : (b0 + ob);
}

// ---------------------------------------------------------------------------
// k_packall: all weight pre-packs fused + bcnt zero-init.
// [R15 A/B: merging this into k_bin + separate memset REGRESSED (+3.2us) --
//  the extra memset dispatch costs more than the merge saves. Keep separate.]
// ---------------------------------------------------------------------------
__device__ __forceinline__ ushort16 packp_val(const float* __restrict__ w, int i) {
    const int j  = i & 7;
    const int ln = (i >> 3) & 63;
    const int s  = (i >> 9) & 7;
    const int cc = i >> 12;
    const int k  = s * 32 + ((ln >> 4) * 8) + j;    // zcat idx (k-dim)
    const int n  = cc * 16 + (ln & 15);             // output col
    return f2bf(w[(k >> 2) * 256 + (k & 3) * 64 + n]);
}

__global__ __launch_bounds__(256) void k_packall(
    const float* __restrict__ w1, const float* __restrict__ w2,
    const float* __restrict__ wc1, const float* __restrict__ wc2,
    const float* __restrict__ wl3,
    ushort16* __restrict__ pw12, ushort16* __restrict__ pwc1,
    ushort16* __restrict__ pwc2, ushort16* __restrict__ pwl3,
    int* __restrict__ bcnt)
{
    const int gid = blockIdx.x * 256 + threadIdx.x;
    if (gid < 16384) {
        const int i = gid;
        const int j  = i & 7;
        const int ln = (i >> 3) & 63;
        const int s  = (i >> 9) & 3;
        const int cc = i >> 11;
        const int k  = s * 32 + ((ln >> 4) * 8) + j;    // 0..127
        const int n  = cc * 16 + (ln & 15);             // 0..127
        pw12[i] = f2bf((n < 64) ? w1[k * 64 + n] : w2[k * 64 + (n - 64)]);
    } else if (gid < 32768) {
        pwc1[gid - 16384] = packp_val(wc1, gid - 16384);
    } else if (gid < 49152) {
        pwc2[gid - 32768] = packp_val(wc2, gid - 32768);
    } else if (gid < 53248) {
        const int i = gid - 49152;                      // 0..4095
        const int j  = i & 7;
        const int ln = (i >> 3) & 63;
        const int s  = (i >> 9) & 1;
        const int cc = i >> 10;                         // 0..3
        const int k  = s * 32 + ((ln >> 4) * 8) + j;    // 0..63
        const int n  = cc * 16 + (ln & 15);             // 0..63
        pwl3[i] = f2bf(wl3[k * 64 + n]);
    } else if (gid < 53504) {
        bcnt[gid - 53248] = 0;
    }
}

// ---------------------------------------------------------------------------
// CSR build pass A: k_bin appends edges into bucket-PADDED `pairs`.
// ---------------------------------------------------------------------------
__global__ __launch_bounds__(256) void k_bin(const int* __restrict__ ei,
                                             int* __restrict__ bcnt,
                                             uint32* __restrict__ pairs)
{
    __shared__ int hist[NBUCK];
    __shared__ int gbase[NBUCK];
    const int t = threadIdx.x;
    const int base = blockIdx.x * EPB;

    for (int b = t; b < NBUCK; b += 256) hist[b] = 0;
    __syncthreads();

    uint32 pk[16];
    int bk[16], rk[16];
#pragma unroll
    for (int k = 0; k < 16; ++k) {
        const int e = base + k * 256 + t;
        if (e < NE) {
            const int s = ei[e];
            const int d = ei[NE + e];
            bk[k] = d >> 8;
            pk[k] = (uint32)s | ((uint32)(d & 255) << 16);
            rk[k] = atomicAdd(&hist[bk[k]], 1);
        }
    }
    __syncthreads();

    for (int b = t; b < NBUCK; b += 256)
        gbase[b] = hist[b] ? atomicAdd(&bcnt[b], hist[b]) : 0;
    __syncthreads();

#pragma unroll
    for (int k = 0; k < 16; ++k) {
        const int e = base + k * 256 + t;
        if (e < NE) pairs[(size_t)bk[k] * BCAP + gbase[bk[k]] + rk[k]] = pk[k];
    }
}

// ---------------------------------------------------------------------------
// binscat body (one block per bucket): derives bucket bases + per-node
// row_ptr in-block and scatters ssrc within its ~16KB window.
// ---------------------------------------------------------------------------
__device__ void binscat_body(const int bid,
                             const uint32* __restrict__ pairs,
                             const int* __restrict__ bcnt,
                             int* __restrict__ row_ptr,
                             int* __restrict__ ssrc)
{
    __shared__ int sb[256];
    __shared__ int hist[256];
    __shared__ int s[256];
    __shared__ int lptr[256];
    __shared__ int lcur[256];
    const int b = bid;
    const int t = threadIdx.x;
    const int total = bcnt[b];
    const uint32* pb = pairs + (size_t)b * BCAP;

    // bucket-level exclusive base via block-local scan of all bucket counts
    sb[t] = (t < NBUCK) ? bcnt[t] : 0;
    __syncthreads();
    for (int off = 1; off < 256; off <<= 1) {
        const int v = (t >= off) ? sb[t - off] : 0;
        __syncthreads();
        sb[t] += v;
        __syncthreads();
    }
    const int base = sb[b] - total;
    if (b == 0 && t == 0) row_ptr[NN] = NE;

    hist[t] = 0;
    __syncthreads();
    for (int e = t; e < total; e += 256) atomicAdd(&hist[pb[e] >> 16], 1);
    __syncthreads();

    const int v = hist[t];
    s[t] = v;
    __syncthreads();
    for (int off = 1; off < 256; off <<= 1) {
        const int u = (t >= off) ? s[t - off] : 0;
        __syncthreads();
        s[t] += u;
        __syncthreads();
    }
    const int excl = base + s[t] - v;
    lptr[t] = excl;
    lcur[t] = 0;
    const int n = (b << 8) + t;
    if (n < NN) row_ptr[n] = excl;
    __syncthreads();

    for (int e = t; e < total; e += 256) {
        const uint32 p = pb[e];
        const int d = p >> 16;
        const int r = atomicAdd(&lcur[d], 1);
        ssrc[lptr[d] + r] = (int)(p & 0xffffu);
    }
}

// ---------------------------------------------------------------------------
// lin12 body (MFMA): [a_bf16 | skip] = x @ [W1 | W2] + [b1 | b2], with the
// attention projection t = a @ u fused into the epilogue.
// ---------------------------------------------------------------------------
__device__ void lin12_body(const int bid,
                           const float* __restrict__ x,
                           const ushort16* __restrict__ pw,
                           const float* __restrict__ b1,
                           const float* __restrict__ b2,
                           const float* __restrict__ u,
                           ushort16* __restrict__ ab,
                           float* __restrict__ skip,
                           float* __restrict__ tOut)
{
    const int tid = threadIdx.x;
    const int lane = tid & 63;
    const int g = tid >> 6;
    const int m = lane & 15;
    const int quad = lane >> 4;
    const int rowBase = bid * 64 + g * 16;

    const int arow = min(rowBase + m, NN - 1);
    const float* xr = x + (size_t)arow * 128 + quad * 8;

    f32x4 acc[8];
#pragma unroll
    for (int c = 0; c < 8; ++c)
#pragma unroll
        for (int r = 0; r < 4; ++r) acc[c][r] = 0.f;

#pragma unroll
    for (int s = 0; s < 4; ++s) {
        const float4 xa = *(const float4*)(xr + s * 32);
        const float4 xb = *(const float4*)(xr + s * 32 + 4);
        const bf16x8 af = pack8(xa, xb);
#pragma unroll
        for (int c = 0; c < 8; ++c) {
            const bf16x8 bf = *(const bf16x8*)&pw[((c * 4 + s) * 64 + lane) * 8];
            acc[c] = __builtin_amdgcn_mfma_f32_16x16x32_bf16(af, bf, acc[c], 0, 0, 0);
        }
    }

    float tl[16];
#pragma unroll
    for (int i = 0; i < 16; ++i) tl[i] = 0.f;

#pragma unroll
    for (int c = 0; c < 8; ++c) {
        const int colg = c * 16 + m;
        const float bv = (colg < 64) ? b1[colg] : b2[colg - 64];
#pragma unroll
        for (int reg = 0; reg < 4; ++reg) {
            const float v = acc[c][reg] + bv;
            const int gr = rowBase + quad * 4 + reg;
            if (gr < NN) {
                if (c < 4) ab[gr * 64 + colg] = f2bf(v);
                else       skip[gr * 64 + (colg - 64)] = v;
            }
            if (c < 4) {
                const float4 uv = ((const float4*)u)[colg];
                tl[reg * 4 + 0] += v * uv.x;
                tl[reg * 4 + 1] += v * uv.y;
                tl[reg * 4 + 2] += v * uv.z;
                tl[reg * 4 + 3] += v * uv.w;
            }
        }
    }

    const float tv = multireduce16(tl, m);
    const int gidx = rowBase * 4 + (quad << 4) + m;  // = row*4 + h, contiguous
    if (gidx < NN * 4) tOut[gidx] = tv;
}

// ---------------------------------------------------------------------------
// k_bslin: MERGED binscat + lin12 (independent work, block-partitioned).
// ---------------------------------------------------------------------------
__global__ __launch_bounds__(256) void k_bslin(
    const uint32* __restrict__ pairs, const int* __restrict__ bcnt,
    int* __restrict__ row_ptr, int* __restrict__ ssrc,
    const float* __restrict__ x, const ushort16* __restrict__ pw,
    const float* __restrict__ b1, const float* __restrict__ b2,
    const float* __restrict__ u,
    ushort16* __restrict__ ab, float* __restrict__ skip,
    float* __restrict__ tOut)
{
    if (blockIdx.x < NBUCK) {
        binscat_body(blockIdx.x, pairs, bcnt, row_ptr, ssrc);
    } else {
        lin12_body(blockIdx.x - NBUCK, x, pw, b1, b2, u, ab, skip, tOut);
    }
}

// ---------------------------------------------------------------------------
// k_aggpost: FUSED aggregation + post-GEMM (+ optional fused lin3).
// Block = 16 nodes, 4 waves x 4 nodes/wave. Per-wave phase 0: softmax q for
// own 4 nodes' edges -> {q1,q2,q3,src} in LDS (q0 = invdeg-q1-q2-q3).
// Phase 1: R7's proven half-split body (32 lanes/edge, 2ch/lane), 8/2/1
// ladder, with PACKED f32x2 accumulation (v_pk_fma_f32: 4 pk-FMA/edge/lane
// instead of 8 scalar FMA; identical arithmetic).
// Phase 2: 16x256 LDS tile -> MFMA post-GEMM + bias + skip + relu (+fused t).
//   Layer-1 mode additionally runs lin3 (h @ W3 + b3 -> skip) in-block.
// LDS ~19.3 KB -> 8 blocks/CU (thread-cap-limited anyway).
// ---------------------------------------------------------------------------
__global__ __launch_bounds__(256) void k_aggpost(
    const int* __restrict__ row_ptr, const int* __restrict__ ssrc,
    const float* __restrict__ t, const uint32* __restrict__ abu,
    const float* __restrict__ c,
    const ushort16* __restrict__ pw, const float* __restrict__ bias,
    float* skip,
    float* __restrict__ out, ushort16* __restrict__ outb,
    const float* __restrict__ uproj, float* __restrict__ tOut,
    const ushort16* __restrict__ pwl3, const float* __restrict__ b3)
{
    __shared__ float4 ql[QCAP];         // 8 KB: {q1,q2,q3, src_bits}
    __shared__ char zl[16 * 512];       // 8 KB: 16 nodes x 256 bf16, swizzled
    __shared__ char hl[16 * 128];       // 2 KB: h bf16 tile for fused lin3
    __shared__ float t_lds[4][64];
    __shared__ float4 tnode[16];
    __shared__ float invdegs[16];

    const int tid = threadIdx.x;
    const int lane = tid & 63;
    const int w = tid >> 6;
    const int half = lane >> 5;
    const int u = lane & 31;
    const int nodeBase = blockIdx.x * 16;

    const float4 tc = *(const float4*)c;

    // per-wave row_ptr boundaries: lanes 0..4 -> own nodes, 5 -> block start,
    // 6 -> block end (nodeBase+16).
    int rr = 0;
    if (lane < 7) {
        const int off = (lane < 5) ? (w * 4 + lane) : ((lane == 5) ? 0 : 16);
        rr = row_ptr[nodeBase + off];
    }
    const int rp0 = __shfl(rr, 0, 64);
    const int rp1 = __shfl(rr, 1, 64);
    const int rp2 = __shfl(rr, 2, 64);
    const int rp3 = __shfl(rr, 3, 64);
    const int rp4 = __shfl(rr, 4, 64);
    const int r0b = __shfl(rr, 5, 64);
    const int r1b = __shfl(rr, 6, 64);

    if (lane < 4) {
        tnode[w * 4 + lane] = ((const float4*)t)[nodeBase + w * 4 + lane];
        const int a = (lane == 0) ? rp0 : (lane == 1) ? rp1 : (lane == 2) ? rp2 : rp3;
        const int b = (lane == 0) ? rp1 : (lane == 1) ? rp2 : (lane == 2) ? rp3 : rp4;
        invdegs[w * 4 + lane] = (b > a) ? 1.f / (float)(b - a) : 0.f;
    }

    const bool fit = (r1b - r0b) <= QCAP;

    // ---- phase 0 (per-wave): q for own segment [rp0, rp4) -> LDS slice ----
    if (fit) {
        for (int i = rp0 + lane; i < rp4; i += 64) {
            const int se = ssrc[i];
            const int dl = (i >= rp1) + (i >= rp2) + (i >= rp3);
            const float4 ts = ((const float4*)t)[se];
            const float4 q = softq(ts, tnode[w * 4 + dl], tc, invdegs[w * 4 + dl]);
            ql[i - r0b] = make_float4(q.y, q.z, q.w, __int_as_float(se));
        }
    }

    // ---- phase 1: half-split 8/2/1 ladder, packed f32x2 accumulation ----
#define ACCUM3(QA, AV)                                                 \
    {                                                                  \
        const float q0 = invdeg - (QA).x - (QA).y - (QA).z;            \
        f32x2 vv; vv[0] = bf_lo(AV); vv[1] = bf_hi(AV);                \
        zz0 = __builtin_elementwise_fma(vv, splat2(q0), zz0);          \
        zz1 = __builtin_elementwise_fma(vv, splat2((QA).x), zz1);      \
        zz2 = __builtin_elementwise_fma(vv, splat2((QA).y), zz2);      \
        zz3 = __builtin_elementwise_fma(vv, splat2((QA).z), zz3);      \
    }
#define ACCUM4(Q4, AV)                                                 \
    {                                                                  \
        f32x2 vv; vv[0] = bf_lo(AV); vv[1] = bf_hi(AV);                \
        zz0 = __builtin_elementwise_fma(vv, splat2((Q4).x), zz0);      \
        zz1 = __builtin_elementwise_fma(vv, splat2((Q4).y), zz1);      \
        zz2 = __builtin_elementwise_fma(vv, splat2((Q4).z), zz2);      \
        zz3 = __builtin_elementwise_fma(vv, splat2((Q4).w), zz3);      \
    }

#pragma unroll
    for (int nn = 0; nn < 4; ++nn) {
        const int nloc = w * 4 + nn;
        const int r0 = (nn == 0) ? rp0 : (nn == 1) ? rp1 : (nn == 2) ? rp2 : rp3;
        const int r1 = (nn == 0) ? rp1 : (nn == 1) ? rp2 : (nn == 2) ? rp3 : rp4;
        const float invdeg = (r1 > r0) ? 1.f / (float)(r1 - r0) : 0.f;

        f32x2 zz0 = {0.f, 0.f}, zz1 = {0.f, 0.f};
        f32x2 zz2 = {0.f, 0.f}, zz3 = {0.f, 0.f};

        if (fit) {
            const float4* qb = ql - r0b;
            int idx = r0;
            for (; idx + 7 < r1; idx += 8) {
                const float4 qa0 = qb[idx + half];
                const float4 qa1 = qb[idx + 2 + half];
                const float4 qa2 = qb[idx + 4 + half];
                const float4 qa3 = qb[idx + 6 + half];
                const uint32 av0 = abu[__float_as_int(qa0.w) * 32 + u];
                const uint32 av1 = abu[__float_as_int(qa1.w) * 32 + u];
                const uint32 av2 = abu[__float_as_int(qa2.w) * 32 + u];
                const uint32 av3 = abu[__float_as_int(qa3.w) * 32 + u];
                ACCUM3(qa0, av0) ACCUM3(qa1, av1)
                ACCUM3(qa2, av2) ACCUM3(qa3, av3)
            }
            for (; idx + 1 < r1; idx += 2) {
                const float4 qa = qb[idx + half];
                const uint32 av = abu[__float_as_int(qa.w) * 32 + u];
                ACCUM3(qa, av)
            }
            if (idx < r1 && half == 0) {
                const float4 qa = qb[idx];
                const uint32 av = abu[__float_as_int(qa.w) * 32 + u];
                ACCUM3(qa, av)
            }
        } else {
            // never-taken in practice: recompute q inline (no LDS capacity)
            const float4 td = tnode[nloc];
            int idx = r0;
            for (; idx + 1 < r1; idx += 2) {
                const int se = ssrc[idx + half];
                const uint32 av = abu[se * 32 + u];
                const float4 q4 = softq(((const float4*)t)[se], td, tc, invdeg);
                ACCUM4(q4, av)
            }
            if (idx < r1 && half == 0) {
                const int se = ssrc[idx];
                const uint32 av = abu[se * 32 + u];
                const float4 q4 = softq(((const float4*)t)[se], td, tc, invdeg);
                ACCUM4(q4, av)
            }
        }
#undef ACCUM3
#undef ACCUM4

        float z00 = zz0[0], z01 = zz0[1];
        float z10 = zz1[0], z11 = zz1[1];
        float z20 = zz2[0], z21 = zz2[1];
        float z30 = zz3[0], z31 = zz3[1];

        z00 += __shfl_xor(z00, 32, 64); z01 += __shfl_xor(z01, 32, 64);
        z10 += __shfl_xor(z10, 32, 64); z11 += __shfl_xor(z11, 32, 64);
        z20 += __shfl_xor(z20, 32, 64); z21 += __shfl_xor(z21, 32, 64);
        z30 += __shfl_xor(z30, 32, 64); z31 += __shfl_xor(z31, 32, 64);

        if (half == 0) {
            uint4 pk;
            pk.x = (uint32)f2bf(z00) | ((uint32)f2bf(z10) << 16);
            pk.y = (uint32)f2bf(z20) | ((uint32)f2bf(z30) << 16);
            pk.z = (uint32)f2bf(z01) | ((uint32)f2bf(z11) << 16);
            pk.w = (uint32)f2bf(z21) | ((uint32)f2bf(z31) << 16);
            *(uint4*)(zl + nloc * 512 + ((u * 16) ^ ((nloc & 7) << 4))) = pk;
        }
    }
    __syncthreads();

    // ---- phase 2: post-GEMM from LDS (wave w -> cols w*16..+15) ----
    const int m = lane & 15;
    const int quad = lane >> 4;

    f32x4 acc;
#pragma unroll
    for (int r = 0; r < 4; ++r) acc[r] = 0.f;

#pragma unroll
    for (int s = 0; s < 8; ++s) {
        const bf16x8 af = *(const bf16x8*)(zl + m * 512 +
                            ((s * 64 + quad * 16) ^ ((m & 7) << 4)));
        const bf16x8 bf = *(const bf16x8*)&pw[((w * 8 + s) * 64 + lane) * 8];
        acc = __builtin_amdgcn_mfma_f32_16x16x32_bf16(af, bf, acc, 0, 0, 0);
    }

    const int colg = w * 16 + m;
    const float bv = bias[colg];

    float tl[16];
#pragma unroll
    for (int i = 0; i < 16; ++i) tl[i] = 0.f;

#pragma unroll
    for (int reg = 0; reg < 4; ++reg) {
        const int gr = nodeBase + quad * 4 + reg;          // always < NN (16|NN)
        const float v = fmaxf(acc[reg] + bv + skip[gr * 64 + colg], 0.f);
        if (out)  out[gr * 64 + colg]  = v;
        if (outb) outb[gr * 64 + colg] = f2bf(v);
        if (pwl3) {
            const int row = quad * 4 + reg;
            *(ushort16*)(hl + ((row * 128 + colg * 2) ^ ((row & 7) << 4))) = f2bf(v);
        }
        if (tOut) {
            const float4 uv = ((const float4*)uproj)[colg];
            tl[reg * 4 + 0] += v * uv.x;
            tl[reg * 4 + 1] += v * uv.y;
            tl[reg * 4 + 2] += v * uv.z;
            tl[reg * 4 + 3] += v * uv.w;
        }
    }

    if (tOut) {
        const float tv = multireduce16(tl, m);   // wave-partial over its 16 cols
        t_lds[w][lane] = tv;
    }
    __syncthreads();

    if (tOut && w == 0) {
        const float tvf = t_lds[0][lane] + t_lds[1][lane] +
                          t_lds[2][lane] + t_lds[3][lane];
        tOut[nodeBase * 4 + lane] = tvf;         // row*4+h, contiguous 64 floats
    }

    // ---- fused lin3 (layer-1 only): skip = h @ W3 + b3 for this block ----
    if (pwl3) {
        f32x4 acc3;
#pragma unroll
        for (int r = 0; r < 4; ++r) acc3[r] = 0.f;
#pragma unroll
        for (int s = 0; s < 2; ++s) {
            const bf16x8 af = *(const bf16x8*)(hl +
                                ((m * 128 + quad * 16 + s * 64) ^ ((m & 7) << 4)));
            const bf16x8 bf = *(const bf16x8*)&pwl3[((w * 2 + s) * 64 + lane) * 8];
            acc3 = __builtin_amdgcn_mfma_f32_16x16x32_bf16(af, bf, acc3, 0, 0, 0);
        }
        const float b3v = b3[colg];
#pragma unroll
        for (int reg = 0; reg < 4; ++reg) {
            const int gr = nodeBase + quad * 4 + reg;
            skip[gr * 64 + colg] = acc3[reg] + b3v;
        }
    }
}

extern "C" void kernel_launch(void* const* d_in, const int* in_sizes, int n_in,
                              void* d_out, int out_size, void* d_ws, size_t ws_size,
                              hipStream_t stream) {
    const float* x       = (const float*)d_in[0];
    const int*   ei      = (const int*)d_in[1];   // [2, NE] int32
    const float* lin1_w  = (const float*)d_in[2];
    const float* lin1_b  = (const float*)d_in[3];
    const float* lin2_w  = (const float*)d_in[4];
    const float* lin2_b  = (const float*)d_in[5];
    const float* lin3_w  = (const float*)d_in[6];
    const float* lin3_b  = (const float*)d_in[7];
    const float* conv1_w = (const float*)d_in[8];
    const float* conv1_u = (const float*)d_in[9];
    const float* conv1_c = (const float*)d_in[10];
    const float* conv1_bias = (const float*)d_in[11];
    const float* conv2_w = (const float*)d_in[12];
    const float* conv2_u = (const float*)d_in[13];
    const float* conv2_c = (const float*)d_in[14];
    const float* conv2_bias = (const float*)d_in[15];
    float* out = (float*)d_out;

    // workspace layout (16B-aligned sections)
    char* p = (char*)d_ws;
    float* skip   = (float*)p;           p += (size_t)NN * 64 * 4;
    float* tt     = (float*)p;           p += (size_t)NN * 4 * 4;   // t (layer 1)
    float* tt2    = (float*)p;           p += (size_t)NN * 4 * 4;   // t (layer 2)
    ushort16* ab  = (ushort16*)p;        p += (size_t)NN * 64 * 2;  // bf16 a
    ushort16* hb  = (ushort16*)p;        p += (size_t)NN * 64 * 2;  // bf16 h
    ushort16* pw12 = (ushort16*)p;       p += 16384 * 2;            // packed [W1|W2]
    ushort16* pwc1 = (ushort16*)p;       p += 16384 * 2;            // packed conv1_w
    ushort16* pwc2 = (ushort16*)p;       p += 16384 * 2;            // packed conv2_w
    ushort16* pwl3 = (ushort16*)p;       p += 4096 * 2;             // packed lin3_w
    int* ssrc     = (int*)p;             p += (size_t)NE * 4;
    int* row_ptr  = (int*)p;             p += (size_t)(NN + 1) * 4;
    int* bcnt     = (int*)p;             p += 256 * 4;              // bucket cursors
    uint32* pairs = (uint32*)p;          p += (size_t)NBUCK * BCAP * 4; // padded bins

    // ---- weight pre-pack + bcnt zero + CSR pass A ----
    k_packall<<<209, 256, 0, stream>>>(lin1_w, lin2_w, conv1_w, conv2_w, lin3_w,
                                       pw12, pwc1, pwc2, pwl3, bcnt);
    k_bin<<<(NE + EPB - 1) / EPB, 256, 0, stream>>>(ei, bcnt, pairs);

    // ---- merged CSR scatter + lin12 (independent, one dispatch) ----
    k_bslin<<<NBUCK + LIN12_BLOCKS, 256, 0, stream>>>(pairs, bcnt, row_ptr, ssrc,
                                                      x, pw12, lin1_b, lin2_b,
                                                      conv1_u, ab, skip, tt);

    // ---- layer 1: fused agg + post + t2-projection + lin3 ----
    k_aggpost<<<NN / 16, 256, 0, stream>>>(row_ptr, ssrc, tt,
                                           (const uint32*)ab, conv1_c,
                                           pwc1, conv1_bias, skip,
                                           nullptr, hb, conv2_u, tt2,
                                           pwl3, lin3_b);

    // ---- layer 2 ----
    k_aggpost<<<NN / 16, 256, 0, stream>>>(row_ptr, ssrc, tt2,
                                           (const uint32*)hb, conv2_c,
                                           pwc2, conv2_bias, skip,
                                           out, nullptr, nullptr, nullptr,
                                           nullptr, nullptr);
}